// Round 16
// baseline (162.772 us; speedup 1.0000x reference)
//
#include <hip/hip_runtime.h>
#include <hip/hip_bf16.h>

// Problem constants (fixed by setup_inputs)
constexpr int Bc  = 8;
constexpr int Qn  = 900;
constexpr int Sn  = 21760;

__constant__ int LVL_START[4] = {0, 16384, 20480, 21504};

typedef __attribute__((ext_vector_type(8))) short short8;
typedef __attribute__((ext_vector_type(4))) float f32x4;
typedef __attribute__((ext_vector_type(4))) unsigned short u16x4;

__device__ __forceinline__ unsigned short f2bf(float x) {
    union { float f; unsigned int u; } z; z.f = x;
    unsigned int r = (z.u + 0x7FFF + ((z.u >> 16) & 1)) >> 16;   // RTN-even
    return (unsigned short)r;
}
__device__ __forceinline__ float bf2f(unsigned short u) {
    union { unsigned int i; float f; } z;
    z.i = ((unsigned int)u) << 16;
    return z.f;
}

// ---------------------------------------------------------------------------
// Single pre-pass packing all four weights into bf16 MFMA fragment order.
// Block roles: 0-31 Wv(256) | 32-63 Wout(256) | 64-95 Wo(256) | 96-111 Wa(128).
// frag layout: frag_id = ntile*8 + kstep; lane l supplies
// W[k = kstep*32 + (l>>4)*8 + j][n = ntile*16 + (l&15)], j=0..7.
__global__ __launch_bounds__(256) void wfrag_all(const float* __restrict__ Wv,
                                                 const float* __restrict__ Wout,
                                                 const float* __restrict__ Wo,
                                                 const float* __restrict__ Wa,
                                                 unsigned short* __restrict__ fV,
                                                 unsigned short* __restrict__ fO,
                                                 unsigned short* __restrict__ fQK) {
    int blk = blockIdx.x;
    const float* W; unsigned short* out; int N, base;
    if      (blk < 32) { W = Wv;   out = fV;           N = 256; base = 0;  }
    else if (blk < 64) { W = Wout; out = fO;           N = 256; base = 32; }
    else if (blk < 96) { W = Wo;   out = fQK;          N = 256; base = 64; }
    else               { W = Wa;   out = fQK + 65536;  N = 128; base = 96; }
    int gid = (blk - base) * 256 + threadIdx.x;
    int frag = gid >> 6, lane = gid & 63;
    int ntile = frag >> 3, s = frag & 7;
    int n = ntile * 16 + (lane & 15);
    int kb = s * 32 + (lane >> 4) * 8;
    unsigned short* o = out + (size_t)gid * 8;
#pragma unroll
    for (int j = 0; j < 8; ++j)
        o[j] = f2bf(W[(size_t)(kb + j) * N + n]);
}

// ---------------------------------------------------------------------------
// UBER GEMM: one dispatch, two block roles.
//   blocks 0..2719   : value = ehs @ W_value + b  (bf16 out, NT load/store)
//   blocks 2720..2832: {off_raw, logits} = (hidden+pos) @ {W_off, W_attn}
// Value role pinned ~105us across r6-r14 (all pipes <25%) — consistent with
// an effective ~2.5 TB/s L3/HBM read-path rate on its 267 MB stream. NT hints
// here are a cheap probe of that theory (neutral if true, +5-10% if L2-thrash).
__global__ __launch_bounds__(512) void uber_gemm(
        const float* __restrict__ Aehs, const unsigned short* __restrict__ WfragV,
        const float* __restrict__ bv, unsigned short* __restrict__ Cval,
        const float* __restrict__ A1, const float* __restrict__ A2,
        const unsigned short* __restrict__ WfragQK,
        const float* __restrict__ bo, const float* __restrict__ ba,
        float* __restrict__ off_raw, float* __restrict__ logits, int Mqk) {
    __shared__ unsigned short As[64 * 256];   // 32 KB bf16, XOR-swizzled rows

    const int t    = threadIdx.x;
    const int lane = t & 63;
    const int w    = t >> 6;                  // 0..7
    const int wr   = w >> 2, wc = w & 3;      // wave grid 2x4
    const int lq   = lane >> 4, lr = lane & 15;

    if (blockIdx.x < 2720) {
        // ================= VALUE role =================
        const int bm = blockIdx.x;
        const f32x4* A4 = reinterpret_cast<const f32x4*>(Aehs + (size_t)bm * 64 * 256);
#pragma unroll
        for (int i = 0; i < 4; ++i) {
            int c = i * 512 + t;
            int row = c >> 5;
            int kus = (c & 31) * 8;
            f32x4 v0 = __builtin_nontemporal_load(&A4[c * 2]);
            f32x4 v1 = __builtin_nontemporal_load(&A4[c * 2 + 1]);
            union { short8 v; unsigned short u[8]; } pk;
            pk.u[0] = f2bf(v0.x); pk.u[1] = f2bf(v0.y); pk.u[2] = f2bf(v0.z); pk.u[3] = f2bf(v0.w);
            pk.u[4] = f2bf(v1.x); pk.u[5] = f2bf(v1.y); pk.u[6] = f2bf(v1.z); pk.u[7] = f2bf(v1.w);
            int idx = row * 256 + (kus ^ ((row & 7) << 3));
            *reinterpret_cast<short8*>(&As[idx]) = pk.v;
        }

        f32x4 acc[2][4];
#pragma unroll
        for (int mt = 0; mt < 2; ++mt)
#pragma unroll
            for (int nt = 0; nt < 4; ++nt) acc[mt][nt] = (f32x4){0.f, 0.f, 0.f, 0.f};

        __syncthreads();

#pragma unroll 2
        for (int s = 0; s < 8; ++s) {
            short8 bfr[4];
#pragma unroll
            for (int nt = 0; nt < 4; ++nt) {
                int ntile = wc * 4 + nt;
                size_t off = ((size_t)((ntile * 8 + s) * 64 + lane)) * 8;
                bfr[nt] = *reinterpret_cast<const short8*>(WfragV + off);
            }
            const int kus = s * 32 + lq * 8;
#pragma unroll
            for (int mt = 0; mt < 2; ++mt) {
                int r   = wr * 32 + mt * 16 + lr;
                int idx = r * 256 + (kus ^ ((r & 7) << 3));
                short8 a = *reinterpret_cast<const short8*>(&As[idx]);
#pragma unroll
                for (int nt = 0; nt < 4; ++nt)
                    acc[mt][nt] = __builtin_amdgcn_mfma_f32_16x16x32_bf16(bfr[nt], a, acc[mt][nt], 0, 0, 0);
            }
        }

#pragma unroll
        for (int nt = 0; nt < 4; ++nt) {
            int n0 = wc * 64 + nt * 16 + lq * 4;
            float4 bb = *reinterpret_cast<const float4*>(&bv[n0]);
#pragma unroll
            for (int mt = 0; mt < 2; ++mt) {
                int row = bm * 64 + wr * 32 + mt * 16 + lr;
                u16x4 o;
                o.x = f2bf(acc[mt][nt][0] + bb.x);
                o.y = f2bf(acc[mt][nt][1] + bb.y);
                o.z = f2bf(acc[mt][nt][2] + bb.z);
                o.w = f2bf(acc[mt][nt][3] + bb.w);
                __builtin_nontemporal_store(o, reinterpret_cast<u16x4*>(&Cval[(size_t)row * 256 + n0]));
            }
        }
    } else {
        // ================= QK role =================
        const int bm = blockIdx.x - 2720;
        const int maxr = Mqk - bm * 64;

        const float4* A14 = reinterpret_cast<const float4*>(A1 + (size_t)bm * 64 * 256);
        const float4* A24 = reinterpret_cast<const float4*>(A2 + (size_t)bm * 64 * 256);
#pragma unroll
        for (int i = 0; i < 4; ++i) {
            int c = i * 512 + t;
            int row = c >> 5;
            int kus = (c & 31) * 8;
            float4 v0 = make_float4(0.f,0.f,0.f,0.f), v1 = v0;
            if (row < maxr) {
                float4 x0 = A14[c * 2], y0 = A24[c * 2];
                float4 x1 = A14[c * 2 + 1], y1 = A24[c * 2 + 1];
                v0 = make_float4(x0.x + y0.x, x0.y + y0.y, x0.z + y0.z, x0.w + y0.w);
                v1 = make_float4(x1.x + y1.x, x1.y + y1.y, x1.z + y1.z, x1.w + y1.w);
            }
            union { short8 v; unsigned short u[8]; } pk;
            pk.u[0] = f2bf(v0.x); pk.u[1] = f2bf(v0.y); pk.u[2] = f2bf(v0.z); pk.u[3] = f2bf(v0.w);
            pk.u[4] = f2bf(v1.x); pk.u[5] = f2bf(v1.y); pk.u[6] = f2bf(v1.z); pk.u[7] = f2bf(v1.w);
            int idx = row * 256 + (kus ^ ((row & 7) << 3));
            *reinterpret_cast<short8*>(&As[idx]) = pk.v;
        }

        f32x4 acc[2][6];
#pragma unroll
        for (int mt = 0; mt < 2; ++mt)
#pragma unroll
            for (int nt = 0; nt < 6; ++nt) acc[mt][nt] = (f32x4){0.f, 0.f, 0.f, 0.f};

        __syncthreads();

#pragma unroll 2
        for (int s = 0; s < 8; ++s) {
            short8 bfr[6];
#pragma unroll
            for (int nt = 0; nt < 6; ++nt) {
                int ntc = wc * 6 + nt;                // 0..23
                const unsigned short* p = (ntc < 16)
                    ? WfragQK + ((size_t)(ntc * 8 + s)) * 512
                    : WfragQK + 65536 + ((size_t)((ntc - 16) * 8 + s)) * 512;
                bfr[nt] = *reinterpret_cast<const short8*>(p + lane * 8);
            }
            const int kus = s * 32 + lq * 8;
#pragma unroll
            for (int mt = 0; mt < 2; ++mt) {
                int r   = wr * 32 + mt * 16 + lr;
                int idx = r * 256 + (kus ^ ((r & 7) << 3));
                short8 a = *reinterpret_cast<const short8*>(&As[idx]);
#pragma unroll
                for (int nt = 0; nt < 6; ++nt)
                    acc[mt][nt] = __builtin_amdgcn_mfma_f32_16x16x32_bf16(bfr[nt], a, acc[mt][nt], 0, 0, 0);
            }
        }

#pragma unroll
        for (int nt = 0; nt < 6; ++nt) {
            int ntc = wc * 6 + nt;
            float* base; int stride, n0;
            float4 bb;
            if (ntc < 16) { n0 = ntc * 16 + lq * 4;        base = off_raw; stride = 256;
                            bb = *reinterpret_cast<const float4*>(&bo[n0]); }
            else          { n0 = (ntc - 16) * 16 + lq * 4; base = logits;  stride = 128;
                            bb = *reinterpret_cast<const float4*>(&ba[n0]); }
#pragma unroll
            for (int mt = 0; mt < 2; ++mt) {
                int r = wr * 32 + mt * 16 + lr;
                if (r < maxr) {
                    int row = bm * 64 + r;
                    float4 o = make_float4(acc[mt][nt][0] + bb.x, acc[mt][nt][1] + bb.y,
                                           acc[mt][nt][2] + bb.z, acc[mt][nt][3] + bb.w);
                    *reinterpret_cast<float4*>(&base[(size_t)row * stride + n0]) = o;
                }
            }
        }
    }
}

// ---------------------------------------------------------------------------
// out = out_pre @ W_out + b via bf16 MFMA, f32 output. M=7200, row-guarded.
__global__ __launch_bounds__(512) void gemm_out_mfma(const float* __restrict__ A,
                                                     const unsigned short* __restrict__ Wfrag,
                                                     const float* __restrict__ bias,
                                                     float* __restrict__ C, int M) {
    __shared__ unsigned short As[64 * 256];

    const int t  = threadIdx.x;
    const int bm = blockIdx.x;
    const int maxr = M - bm * 64;

    const float4* A4 = reinterpret_cast<const float4*>(A + (size_t)bm * 64 * 256);
#pragma unroll
    for (int i = 0; i < 4; ++i) {
        int c = i * 512 + t;
        int row = c >> 5;
        int kus = (c & 31) * 8;
        float4 v0 = make_float4(0.f,0.f,0.f,0.f), v1 = v0;
        if (row < maxr) { v0 = A4[c * 2]; v1 = A4[c * 2 + 1]; }
        union { short8 v; unsigned short u[8]; } pk;
        pk.u[0] = f2bf(v0.x); pk.u[1] = f2bf(v0.y); pk.u[2] = f2bf(v0.z); pk.u[3] = f2bf(v0.w);
        pk.u[4] = f2bf(v1.x); pk.u[5] = f2bf(v1.y); pk.u[6] = f2bf(v1.z); pk.u[7] = f2bf(v1.w);
        int idx = row * 256 + (kus ^ ((row & 7) << 3));
        *reinterpret_cast<short8*>(&As[idx]) = pk.v;
    }

    const int lane = t & 63;
    const int w    = t >> 6;
    const int wr   = w >> 2, wc = w & 3;
    const int lq   = lane >> 4, lr = lane & 15;

    f32x4 acc[2][4];
#pragma unroll
    for (int mt = 0; mt < 2; ++mt)
#pragma unroll
        for (int nt = 0; nt < 4; ++nt) acc[mt][nt] = (f32x4){0.f, 0.f, 0.f, 0.f};

    __syncthreads();

#pragma unroll 2
    for (int s = 0; s < 8; ++s) {
        short8 bfr[4];
#pragma unroll
        for (int nt = 0; nt < 4; ++nt) {
            int ntile = wc * 4 + nt;
            size_t off = ((size_t)((ntile * 8 + s) * 64 + lane)) * 8;
            bfr[nt] = *reinterpret_cast<const short8*>(Wfrag + off);
        }
        const int kus = s * 32 + lq * 8;
#pragma unroll
        for (int mt = 0; mt < 2; ++mt) {
            int r   = wr * 32 + mt * 16 + lr;
            int idx = r * 256 + (kus ^ ((r & 7) << 3));
            short8 a = *reinterpret_cast<const short8*>(&As[idx]);
#pragma unroll
            for (int nt = 0; nt < 4; ++nt)
                acc[mt][nt] = __builtin_amdgcn_mfma_f32_16x16x32_bf16(bfr[nt], a, acc[mt][nt], 0, 0, 0);
        }
    }

#pragma unroll
    for (int nt = 0; nt < 4; ++nt) {
        int n0 = wc * 64 + nt * 16 + lq * 4;
        float4 bb = *reinterpret_cast<const float4*>(&bias[n0]);
#pragma unroll
        for (int mt = 0; mt < 2; ++mt) {
            int r = wr * 32 + mt * 16 + lr;
            if (r < maxr) {
                int row = bm * 64 + r;
                float4 o = make_float4(acc[mt][nt][0] + bb.x, acc[mt][nt][1] + bb.y,
                                       acc[mt][nt][2] + bb.z, acc[mt][nt][3] + bb.w);
                *reinterpret_cast<float4*>(&C[(size_t)row * 256 + n0]) = o;
            }
        }
    }
}

// ---------------------------------------------------------------------------
// Fused softmax + bilinear sampling. 16 lanes per (b,q,h) group:
//   ch = L&7 -> 4-channel group; pq = L>>3 -> level-pair half.
__global__ __launch_bounds__(256) void sample_fused_k(const unsigned short* __restrict__ value,
                                                      const float* __restrict__ off_raw,
                                                      const float* __restrict__ refp,
                                                      const float* __restrict__ logits,
                                                      float* __restrict__ attw,
                                                      float* __restrict__ out_pre) {
    const int L    = threadIdx.x & 15;
    const int g    = threadIdx.x >> 4;         // 0..15
    const int idx  = blockIdx.x * 16 + g;      // (b*Q+q)*8 + h, < 57600
    const int h    = idx & 7;
    const int bq   = idx >> 3;
    const int b    = bq / Qn;
    const int ch   = L & 7;
    const int pq   = L >> 3;

    // ---- inline softmax over this group's 16 logits ----
    const float4* lg = reinterpret_cast<const float4*>(logits + (size_t)idx * 16);
    float v[16];
    float4 a0 = lg[0], a1 = lg[1], a2 = lg[2], a3 = lg[3];
    v[0]=a0.x; v[1]=a0.y; v[2]=a0.z; v[3]=a0.w;
    v[4]=a1.x; v[5]=a1.y; v[6]=a1.z; v[7]=a1.w;
    v[8]=a2.x; v[9]=a2.y; v[10]=a2.z; v[11]=a2.w;
    v[12]=a3.x; v[13]=a3.y; v[14]=a3.z; v[15]=a3.w;
    float m = v[0];
#pragma unroll
    for (int i = 1; i < 16; ++i) m = fmaxf(m, v[i]);
    float s = 0.f;
#pragma unroll
    for (int i = 0; i < 16; ++i) { v[i] = __expf(v[i] - m); s += v[i]; }
    float inv = 1.f / s;
#pragma unroll
    for (int i = 0; i < 16; ++i) v[i] *= inv;

    // attw output (B,Q,NH,16): lanes pq==0, ch<4 each write one float4
    if (pq == 0 && ch < 4) {
        float4 o;
        if      (ch == 0) o = make_float4(v[0],  v[1],  v[2],  v[3]);
        else if (ch == 1) o = make_float4(v[4],  v[5],  v[6],  v[7]);
        else if (ch == 2) o = make_float4(v[8],  v[9],  v[10], v[11]);
        else              o = make_float4(v[12], v[13], v[14], v[15]);
        reinterpret_cast<float4*>(attw + (size_t)idx * 16)[ch] = o;
    }

    // this half's 8 weights, statically selected
    float w8[8];
#pragma unroll
    for (int i = 0; i < 8; ++i) w8[i] = (pq == 0) ? v[i] : v[i + 8];

    const ushort4* v4 = reinterpret_cast<const ushort4*>(value);
    const size_t vbase4 = (size_t)b * (Sn * 64) + h * 8 + ch;
    const float* offs = off_raw + (size_t)bq * 256 + h * 32;
    const float* rp   = refp    + (size_t)bq * 8;

    float acc0 = 0.f, acc1 = 0.f, acc2 = 0.f, acc3 = 0.f;

#pragma unroll
    for (int li = 0; li < 2; ++li) {
        const int lvl = pq * 2 + li;
        const int Wl = 128 >> lvl, Hl = 128 >> lvl;
        const float fW = (float)Wl, fH = (float)Hl;
        const float rx = rp[lvl * 2 + 0], ry = rp[lvl * 2 + 1];
        const size_t lb4 = vbase4 + (size_t)LVL_START[lvl] * 64;
#pragma unroll
        for (int p = 0; p < 4; ++p) {
            const float w  = w8[li * 4 + p];
            const float locx = rx + offs[lvl * 8 + p * 2 + 0] / fW;
            const float locy = ry + offs[lvl * 8 + p * 2 + 1] / fH;
            const float x = locx * fW - 0.5f;
            const float y = locy * fH - 0.5f;
            const float x0f = floorf(x), y0f = floorf(y);
            const int x0 = (int)x0f, y0 = (int)y0f;
            const int x1 = x0 + 1, y1 = y0 + 1;
            const float fx = x - x0f, fy = y - y0f;
            const float vx0 = (x0 >= 0 && x0 < Wl) ? 1.f : 0.f;
            const float vx1 = (x1 >= 0 && x1 < Wl) ? 1.f : 0.f;
            const float vy0 = (y0 >= 0 && y0 < Hl) ? 1.f : 0.f;
            const float vy1 = (y1 >= 0 && y1 < Hl) ? 1.f : 0.f;
            const int xc0 = min(max(x0, 0), Wl - 1);
            const int xc1 = min(max(x1, 0), Wl - 1);
            const int yc0 = min(max(y0, 0), Hl - 1);
            const int yc1 = min(max(y1, 0), Hl - 1);
            const float w00 = w * (1.f - fx) * (1.f - fy) * vx0 * vy0;
            const float w01 = w * fx         * (1.f - fy) * vx1 * vy0;
            const float w10 = w * (1.f - fx) * fy         * vx0 * vy1;
            const float w11 = w * fx         * fy         * vx1 * vy1;

            const ushort4 t00 = v4[lb4 + (size_t)(yc0 * Wl + xc0) * 64];
            const ushort4 t01 = v4[lb4 + (size_t)(yc0 * Wl + xc1) * 64];
            const ushort4 t10 = v4[lb4 + (size_t)(yc1 * Wl + xc0) * 64];
            const ushort4 t11 = v4[lb4 + (size_t)(yc1 * Wl + xc1) * 64];

            acc0 += w00 * bf2f(t00.x) + w01 * bf2f(t01.x) + w10 * bf2f(t10.x) + w11 * bf2f(t11.x);
            acc1 += w00 * bf2f(t00.y) + w01 * bf2f(t01.y) + w10 * bf2f(t10.y) + w11 * bf2f(t11.y);
            acc2 += w00 * bf2f(t00.z) + w01 * bf2f(t01.z) + w10 * bf2f(t10.z) + w11 * bf2f(t11.z);
            acc3 += w00 * bf2f(t00.w) + w01 * bf2f(t01.w) + w10 * bf2f(t10.w) + w11 * bf2f(t11.w);
        }
    }

    // reduce the two point-halves (partner = lane^8, within the 16-lane group)
    acc0 += __shfl_xor(acc0, 8);
    acc1 += __shfl_xor(acc1, 8);
    acc2 += __shfl_xor(acc2, 8);
    acc3 += __shfl_xor(acc3, 8);

    if (pq == 0)
        reinterpret_cast<float4*>(out_pre)[(size_t)bq * 64 + h * 8 + ch] =
            make_float4(acc0, acc1, acc2, acc3);
}

// ---------------------------------------------------------------------------
extern "C" void kernel_launch(void* const* d_in, const int* in_sizes, int n_in,
                              void* d_out, int out_size, void* d_ws, size_t ws_size,
                              hipStream_t stream) {
    const float* hidden = (const float*)d_in[0];
    const float* ehs    = (const float*)d_in[1];
    const float* pos    = (const float*)d_in[2];
    const float* refp   = (const float*)d_in[3];
    const float* Wv   = (const float*)d_in[5];
    const float* bv   = (const float*)d_in[6];
    const float* Wo   = (const float*)d_in[7];
    const float* bo   = (const float*)d_in[8];
    const float* Wa   = (const float*)d_in[9];
    const float* ba   = (const float*)d_in[10];
    const float* Wout = (const float*)d_in[11];
    const float* bout = (const float*)d_in[12];

    float* ws = (float*)d_ws;
    unsigned short* WfragQK = (unsigned short*)ws;             // 98,304 bf16 (off + attn at +65536)
    unsigned short* WfragO  = (unsigned short*)(ws + 49152);   // 65,536 bf16
    float* off_raw = ws + 1843200;       // 1,843,200 f32
    float* logits  = ws + 3686400;       //   921,600 f32
    float* out_pre = ws + 4608000;       // 1,843,200 f32
    unsigned short* value = (unsigned short*)(ws + 6451200);  // 44,564,480 bf16
    // WfragV aliases out_pre's region: lifetime [wfrag_all, uber_gemm],
    // out_pre lifetime [sample_fused_k, gemm_out_mfma] — disjoint on the stream.
    unsigned short* WfragV = (unsigned short*)out_pre;         // 65,536 bf16

    float* outv = (float*)d_out;         // (B,Q,D) f32
    float* attw = outv + 1843200;        // (B,Q,NH,NL,NP) f32

    wfrag_all<<<112, 256, 0, stream>>>(Wv, Wout, Wo, Wa, WfragV, WfragO, WfragQK);
    uber_gemm<<<2833, 512, 0, stream>>>(ehs, WfragV, bv, value,
                                        hidden, pos, WfragQK, bo, ba,
                                        off_raw, logits, Bc * Qn);
    sample_fused_k<<<3600, 256, 0, stream>>>(value, off_raw, refp, logits, attw, out_pre);
    gemm_out_mfma<<<113, 512, 0, stream>>>(out_pre, WfragO, bout, outv, Bc * Qn);
}

// Round 17
// 158.268 us; speedup vs baseline: 1.0285x; 1.0285x over previous
//
#include <hip/hip_runtime.h>
#include <hip/hip_bf16.h>

// Problem constants (fixed by setup_inputs)
constexpr int Bc  = 8;
constexpr int Qn  = 900;
constexpr int Sn  = 21760;

__constant__ int LVL_START[4] = {0, 16384, 20480, 21504};

typedef __attribute__((ext_vector_type(8))) short short8;
typedef __attribute__((ext_vector_type(4))) float f32x4;

__device__ __forceinline__ unsigned short f2bf(float x) {
    union { float f; unsigned int u; } z; z.f = x;
    unsigned int r = (z.u + 0x7FFF + ((z.u >> 16) & 1)) >> 16;   // RTN-even
    return (unsigned short)r;
}
__device__ __forceinline__ float bf2f(unsigned short u) {
    union { unsigned int i; float f; } z;
    z.i = ((unsigned int)u) << 16;
    return z.f;
}

// ---------------------------------------------------------------------------
// Single pre-pass packing all four weights into bf16 MFMA fragment order.
// Block roles: 0-31 Wv(256) | 32-63 Wout(256) | 64-95 Wo(256) | 96-111 Wa(128).
__global__ __launch_bounds__(256) void wfrag_all(const float* __restrict__ Wv,
                                                 const float* __restrict__ Wout,
                                                 const float* __restrict__ Wo,
                                                 const float* __restrict__ Wa,
                                                 unsigned short* __restrict__ fV,
                                                 unsigned short* __restrict__ fO,
                                                 unsigned short* __restrict__ fQK) {
    int blk = blockIdx.x;
    const float* W; unsigned short* out; int N, base;
    if      (blk < 32) { W = Wv;   out = fV;           N = 256; base = 0;  }
    else if (blk < 64) { W = Wout; out = fO;           N = 256; base = 32; }
    else if (blk < 96) { W = Wo;   out = fQK;          N = 256; base = 64; }
    else               { W = Wa;   out = fQK + 65536;  N = 128; base = 96; }
    int gid = (blk - base) * 256 + threadIdx.x;
    int frag = gid >> 6, lane = gid & 63;
    int ntile = frag >> 3, s = frag & 7;
    int n = ntile * 16 + (lane & 15);
    int kb = s * 32 + (lane >> 4) * 8;
    unsigned short* o = out + (size_t)gid * 8;
#pragma unroll
    for (int j = 0; j < 8; ++j)
        o[j] = f2bf(W[(size_t)(kb + j) * N + n]);
}

// ---------------------------------------------------------------------------
// UBER GEMM: one dispatch, two block roles.
//   blocks 0..2719   : value = ehs @ W_value + b  (bf16 out)
//   blocks 2720..2832: {off_raw, logits} = (hidden+pos) @ {W_off, W_attn}
// NO nontemporal hints: r16 measured NT stores on value -> 2x HBM write
// amplification (WRITE 98->205 MB) + lost L3 residency for sample_k. Value
// output is CONSUMED downstream — NT is only for no-reuse data.
__global__ __launch_bounds__(512) void uber_gemm(
        const float* __restrict__ Aehs, const unsigned short* __restrict__ WfragV,
        const float* __restrict__ bv, unsigned short* __restrict__ Cval,
        const float* __restrict__ A1, const float* __restrict__ A2,
        const unsigned short* __restrict__ WfragQK,
        const float* __restrict__ bo, const float* __restrict__ ba,
        float* __restrict__ off_raw, float* __restrict__ logits, int Mqk) {
    __shared__ unsigned short As[64 * 256];   // 32 KB bf16, XOR-swizzled rows

    const int t    = threadIdx.x;
    const int lane = t & 63;
    const int w    = t >> 6;                  // 0..7
    const int wr   = w >> 2, wc = w & 3;      // wave grid 2x4
    const int lq   = lane >> 4, lr = lane & 15;

    if (blockIdx.x < 2720) {
        // ================= VALUE role =================
        const int bm = blockIdx.x;
        const float4* A4 = reinterpret_cast<const float4*>(Aehs + (size_t)bm * 64 * 256);
#pragma unroll
        for (int i = 0; i < 4; ++i) {
            int c = i * 512 + t;
            int row = c >> 5;
            int kus = (c & 31) * 8;
            float4 v0 = A4[c * 2], v1 = A4[c * 2 + 1];
            union { short8 v; unsigned short u[8]; } pk;
            pk.u[0] = f2bf(v0.x); pk.u[1] = f2bf(v0.y); pk.u[2] = f2bf(v0.z); pk.u[3] = f2bf(v0.w);
            pk.u[4] = f2bf(v1.x); pk.u[5] = f2bf(v1.y); pk.u[6] = f2bf(v1.z); pk.u[7] = f2bf(v1.w);
            int idx = row * 256 + (kus ^ ((row & 7) << 3));
            *reinterpret_cast<short8*>(&As[idx]) = pk.v;
        }

        f32x4 acc[2][4];
#pragma unroll
        for (int mt = 0; mt < 2; ++mt)
#pragma unroll
            for (int nt = 0; nt < 4; ++nt) acc[mt][nt] = (f32x4){0.f, 0.f, 0.f, 0.f};

        __syncthreads();

#pragma unroll 2
        for (int s = 0; s < 8; ++s) {
            short8 bfr[4];
#pragma unroll
            for (int nt = 0; nt < 4; ++nt) {
                int ntile = wc * 4 + nt;
                size_t off = ((size_t)((ntile * 8 + s) * 64 + lane)) * 8;
                bfr[nt] = *reinterpret_cast<const short8*>(WfragV + off);
            }
            const int kus = s * 32 + lq * 8;
#pragma unroll
            for (int mt = 0; mt < 2; ++mt) {
                int r   = wr * 32 + mt * 16 + lr;
                int idx = r * 256 + (kus ^ ((r & 7) << 3));
                short8 a = *reinterpret_cast<const short8*>(&As[idx]);
#pragma unroll
                for (int nt = 0; nt < 4; ++nt)
                    acc[mt][nt] = __builtin_amdgcn_mfma_f32_16x16x32_bf16(bfr[nt], a, acc[mt][nt], 0, 0, 0);
            }
        }

#pragma unroll
        for (int nt = 0; nt < 4; ++nt) {
            int n0 = wc * 64 + nt * 16 + lq * 4;
            float4 bb = *reinterpret_cast<const float4*>(&bv[n0]);
#pragma unroll
            for (int mt = 0; mt < 2; ++mt) {
                int row = bm * 64 + wr * 32 + mt * 16 + lr;
                ushort4 o;
                o.x = f2bf(acc[mt][nt][0] + bb.x);
                o.y = f2bf(acc[mt][nt][1] + bb.y);
                o.z = f2bf(acc[mt][nt][2] + bb.z);
                o.w = f2bf(acc[mt][nt][3] + bb.w);
                *reinterpret_cast<ushort4*>(&Cval[(size_t)row * 256 + n0]) = o;
            }
        }
    } else {
        // ================= QK role =================
        const int bm = blockIdx.x - 2720;
        const int maxr = Mqk - bm * 64;

        const float4* A14 = reinterpret_cast<const float4*>(A1 + (size_t)bm * 64 * 256);
        const float4* A24 = reinterpret_cast<const float4*>(A2 + (size_t)bm * 64 * 256);
#pragma unroll
        for (int i = 0; i < 4; ++i) {
            int c = i * 512 + t;
            int row = c >> 5;
            int kus = (c & 31) * 8;
            float4 v0 = make_float4(0.f,0.f,0.f,0.f), v1 = v0;
            if (row < maxr) {
                float4 x0 = A14[c * 2], y0 = A24[c * 2];
                float4 x1 = A14[c * 2 + 1], y1 = A24[c * 2 + 1];
                v0 = make_float4(x0.x + y0.x, x0.y + y0.y, x0.z + y0.z, x0.w + y0.w);
                v1 = make_float4(x1.x + y1.x, x1.y + y1.y, x1.z + y1.z, x1.w + y1.w);
            }
            union { short8 v; unsigned short u[8]; } pk;
            pk.u[0] = f2bf(v0.x); pk.u[1] = f2bf(v0.y); pk.u[2] = f2bf(v0.z); pk.u[3] = f2bf(v0.w);
            pk.u[4] = f2bf(v1.x); pk.u[5] = f2bf(v1.y); pk.u[6] = f2bf(v1.z); pk.u[7] = f2bf(v1.w);
            int idx = row * 256 + (kus ^ ((row & 7) << 3));
            *reinterpret_cast<short8*>(&As[idx]) = pk.v;
        }

        f32x4 acc[2][6];
#pragma unroll
        for (int mt = 0; mt < 2; ++mt)
#pragma unroll
            for (int nt = 0; nt < 6; ++nt) acc[mt][nt] = (f32x4){0.f, 0.f, 0.f, 0.f};

        __syncthreads();

#pragma unroll 2
        for (int s = 0; s < 8; ++s) {
            short8 bfr[6];
#pragma unroll
            for (int nt = 0; nt < 6; ++nt) {
                int ntc = wc * 6 + nt;                // 0..23
                const unsigned short* p = (ntc < 16)
                    ? WfragQK + ((size_t)(ntc * 8 + s)) * 512
                    : WfragQK + 65536 + ((size_t)((ntc - 16) * 8 + s)) * 512;
                bfr[nt] = *reinterpret_cast<const short8*>(p + lane * 8);
            }
            const int kus = s * 32 + lq * 8;
#pragma unroll
            for (int mt = 0; mt < 2; ++mt) {
                int r   = wr * 32 + mt * 16 + lr;
                int idx = r * 256 + (kus ^ ((r & 7) << 3));
                short8 a = *reinterpret_cast<const short8*>(&As[idx]);
#pragma unroll
                for (int nt = 0; nt < 6; ++nt)
                    acc[mt][nt] = __builtin_amdgcn_mfma_f32_16x16x32_bf16(bfr[nt], a, acc[mt][nt], 0, 0, 0);
            }
        }

#pragma unroll
        for (int nt = 0; nt < 6; ++nt) {
            int ntc = wc * 6 + nt;
            float* base; int stride, n0;
            float4 bb;
            if (ntc < 16) { n0 = ntc * 16 + lq * 4;        base = off_raw; stride = 256;
                            bb = *reinterpret_cast<const float4*>(&bo[n0]); }
            else          { n0 = (ntc - 16) * 16 + lq * 4; base = logits;  stride = 128;
                            bb = *reinterpret_cast<const float4*>(&ba[n0]); }
#pragma unroll
            for (int mt = 0; mt < 2; ++mt) {
                int r = wr * 32 + mt * 16 + lr;
                if (r < maxr) {
                    int row = bm * 64 + r;
                    float4 o = make_float4(acc[mt][nt][0] + bb.x, acc[mt][nt][1] + bb.y,
                                           acc[mt][nt][2] + bb.z, acc[mt][nt][3] + bb.w);
                    *reinterpret_cast<float4*>(&base[(size_t)row * stride + n0]) = o;
                }
            }
        }
    }
}

// ---------------------------------------------------------------------------
// out = out_pre @ W_out + b via bf16 MFMA, f32 output. M=7200, row-guarded.
__global__ __launch_bounds__(512) void gemm_out_mfma(const float* __restrict__ A,
                                                     const unsigned short* __restrict__ Wfrag,
                                                     const float* __restrict__ bias,
                                                     float* __restrict__ C, int M) {
    __shared__ unsigned short As[64 * 256];

    const int t  = threadIdx.x;
    const int bm = blockIdx.x;
    const int maxr = M - bm * 64;

    const float4* A4 = reinterpret_cast<const float4*>(A + (size_t)bm * 64 * 256);
#pragma unroll
    for (int i = 0; i < 4; ++i) {
        int c = i * 512 + t;
        int row = c >> 5;
        int kus = (c & 31) * 8;
        float4 v0 = make_float4(0.f,0.f,0.f,0.f), v1 = v0;
        if (row < maxr) { v0 = A4[c * 2]; v1 = A4[c * 2 + 1]; }
        union { short8 v; unsigned short u[8]; } pk;
        pk.u[0] = f2bf(v0.x); pk.u[1] = f2bf(v0.y); pk.u[2] = f2bf(v0.z); pk.u[3] = f2bf(v0.w);
        pk.u[4] = f2bf(v1.x); pk.u[5] = f2bf(v1.y); pk.u[6] = f2bf(v1.z); pk.u[7] = f2bf(v1.w);
        int idx = row * 256 + (kus ^ ((row & 7) << 3));
        *reinterpret_cast<short8*>(&As[idx]) = pk.v;
    }

    const int lane = t & 63;
    const int w    = t >> 6;
    const int wr   = w >> 2, wc = w & 3;
    const int lq   = lane >> 4, lr = lane & 15;

    f32x4 acc[2][4];
#pragma unroll
    for (int mt = 0; mt < 2; ++mt)
#pragma unroll
        for (int nt = 0; nt < 4; ++nt) acc[mt][nt] = (f32x4){0.f, 0.f, 0.f, 0.f};

    __syncthreads();

#pragma unroll 2
    for (int s = 0; s < 8; ++s) {
        short8 bfr[4];
#pragma unroll
        for (int nt = 0; nt < 4; ++nt) {
            int ntile = wc * 4 + nt;
            size_t off = ((size_t)((ntile * 8 + s) * 64 + lane)) * 8;
            bfr[nt] = *reinterpret_cast<const short8*>(Wfrag + off);
        }
        const int kus = s * 32 + lq * 8;
#pragma unroll
        for (int mt = 0; mt < 2; ++mt) {
            int r   = wr * 32 + mt * 16 + lr;
            int idx = r * 256 + (kus ^ ((r & 7) << 3));
            short8 a = *reinterpret_cast<const short8*>(&As[idx]);
#pragma unroll
            for (int nt = 0; nt < 4; ++nt)
                acc[mt][nt] = __builtin_amdgcn_mfma_f32_16x16x32_bf16(bfr[nt], a, acc[mt][nt], 0, 0, 0);
        }
    }

#pragma unroll
    for (int nt = 0; nt < 4; ++nt) {
        int n0 = wc * 64 + nt * 16 + lq * 4;
        float4 bb = *reinterpret_cast<const float4*>(&bias[n0]);
#pragma unroll
        for (int mt = 0; mt < 2; ++mt) {
            int r = wr * 32 + mt * 16 + lr;
            if (r < maxr) {
                int row = bm * 64 + r;
                float4 o = make_float4(acc[mt][nt][0] + bb.x, acc[mt][nt][1] + bb.y,
                                       acc[mt][nt][2] + bb.z, acc[mt][nt][3] + bb.w);
                *reinterpret_cast<float4*>(&C[(size_t)row * 256 + n0]) = o;
            }
        }
    }
}

// ---------------------------------------------------------------------------
// Fused softmax + bilinear sampling. 16 lanes per (b,q,h) group:
//   ch = L&7 -> 4-channel group; pq = L>>3 -> level-pair half.
__global__ __launch_bounds__(256) void sample_fused_k(const unsigned short* __restrict__ value,
                                                      const float* __restrict__ off_raw,
                                                      const float* __restrict__ refp,
                                                      const float* __restrict__ logits,
                                                      float* __restrict__ attw,
                                                      float* __restrict__ out_pre) {
    const int L    = threadIdx.x & 15;
    const int g    = threadIdx.x >> 4;         // 0..15
    const int idx  = blockIdx.x * 16 + g;      // (b*Q+q)*8 + h, < 57600
    const int h    = idx & 7;
    const int bq   = idx >> 3;
    const int b    = bq / Qn;
    const int ch   = L & 7;
    const int pq   = L >> 3;

    // ---- inline softmax over this group's 16 logits ----
    const float4* lg = reinterpret_cast<const float4*>(logits + (size_t)idx * 16);
    float v[16];
    float4 a0 = lg[0], a1 = lg[1], a2 = lg[2], a3 = lg[3];
    v[0]=a0.x; v[1]=a0.y; v[2]=a0.z; v[3]=a0.w;
    v[4]=a1.x; v[5]=a1.y; v[6]=a1.z; v[7]=a1.w;
    v[8]=a2.x; v[9]=a2.y; v[10]=a2.z; v[11]=a2.w;
    v[12]=a3.x; v[13]=a3.y; v[14]=a3.z; v[15]=a3.w;
    float m = v[0];
#pragma unroll
    for (int i = 1; i < 16; ++i) m = fmaxf(m, v[i]);
    float s = 0.f;
#pragma unroll
    for (int i = 0; i < 16; ++i) { v[i] = __expf(v[i] - m); s += v[i]; }
    float inv = 1.f / s;
#pragma unroll
    for (int i = 0; i < 16; ++i) v[i] *= inv;

    // attw output (B,Q,NH,16): lanes pq==0, ch<4 each write one float4
    if (pq == 0 && ch < 4) {
        float4 o;
        if      (ch == 0) o = make_float4(v[0],  v[1],  v[2],  v[3]);
        else if (ch == 1) o = make_float4(v[4],  v[5],  v[6],  v[7]);
        else if (ch == 2) o = make_float4(v[8],  v[9],  v[10], v[11]);
        else              o = make_float4(v[12], v[13], v[14], v[15]);
        reinterpret_cast<float4*>(attw + (size_t)idx * 16)[ch] = o;
    }

    // this half's 8 weights, statically selected
    float w8[8];
#pragma unroll
    for (int i = 0; i < 8; ++i) w8[i] = (pq == 0) ? v[i] : v[i + 8];

    const ushort4* v4 = reinterpret_cast<const ushort4*>(value);
    const size_t vbase4 = (size_t)b * (Sn * 64) + h * 8 + ch;
    const float* offs = off_raw + (size_t)bq * 256 + h * 32;
    const float* rp   = refp    + (size_t)bq * 8;

    float acc0 = 0.f, acc1 = 0.f, acc2 = 0.f, acc3 = 0.f;

#pragma unroll
    for (int li = 0; li < 2; ++li) {
        const int lvl = pq * 2 + li;
        const int Wl = 128 >> lvl, Hl = 128 >> lvl;
        const float fW = (float)Wl, fH = (float)Hl;
        const float rx = rp[lvl * 2 + 0], ry = rp[lvl * 2 + 1];
        const size_t lb4 = vbase4 + (size_t)LVL_START[lvl] * 64;
#pragma unroll
        for (int p = 0; p < 4; ++p) {
            const float w  = w8[li * 4 + p];
            const float locx = rx + offs[lvl * 8 + p * 2 + 0] / fW;
            const float locy = ry + offs[lvl * 8 + p * 2 + 1] / fH;
            const float x = locx * fW - 0.5f;
            const float y = locy * fH - 0.5f;
            const float x0f = floorf(x), y0f = floorf(y);
            const int x0 = (int)x0f, y0 = (int)y0f;
            const int x1 = x0 + 1, y1 = y0 + 1;
            const float fx = x - x0f, fy = y - y0f;
            const float vx0 = (x0 >= 0 && x0 < Wl) ? 1.f : 0.f;
            const float vx1 = (x1 >= 0 && x1 < Wl) ? 1.f : 0.f;
            const float vy0 = (y0 >= 0 && y0 < Hl) ? 1.f : 0.f;
            const float vy1 = (y1 >= 0 && y1 < Hl) ? 1.f : 0.f;
            const int xc0 = min(max(x0, 0), Wl - 1);
            const int xc1 = min(max(x1, 0), Wl - 1);
            const int yc0 = min(max(y0, 0), Hl - 1);
            const int yc1 = min(max(y1, 0), Hl - 1);
            const float w00 = w * (1.f - fx) * (1.f - fy) * vx0 * vy0;
            const float w01 = w * fx         * (1.f - fy) * vx1 * vy0;
            const float w10 = w * (1.f - fx) * fy         * vx0 * vy1;
            const float w11 = w * fx         * fy         * vx1 * vy1;

            const ushort4 t00 = v4[lb4 + (size_t)(yc0 * Wl + xc0) * 64];
            const ushort4 t01 = v4[lb4 + (size_t)(yc0 * Wl + xc1) * 64];
            const ushort4 t10 = v4[lb4 + (size_t)(yc1 * Wl + xc0) * 64];
            const ushort4 t11 = v4[lb4 + (size_t)(yc1 * Wl + xc1) * 64];

            acc0 += w00 * bf2f(t00.x) + w01 * bf2f(t01.x) + w10 * bf2f(t10.x) + w11 * bf2f(t11.x);
            acc1 += w00 * bf2f(t00.y) + w01 * bf2f(t01.y) + w10 * bf2f(t10.y) + w11 * bf2f(t11.y);
            acc2 += w00 * bf2f(t00.z) + w01 * bf2f(t01.z) + w10 * bf2f(t10.z) + w11 * bf2f(t11.z);
            acc3 += w00 * bf2f(t00.w) + w01 * bf2f(t01.w) + w10 * bf2f(t10.w) + w11 * bf2f(t11.w);
        }
    }

    // reduce the two point-halves (partner = lane^8, within the 16-lane group)
    acc0 += __shfl_xor(acc0, 8);
    acc1 += __shfl_xor(acc1, 8);
    acc2 += __shfl_xor(acc2, 8);
    acc3 += __shfl_xor(acc3, 8);

    if (pq == 0)
        reinterpret_cast<float4*>(out_pre)[(size_t)bq * 64 + h * 8 + ch] =
            make_float4(acc0, acc1, acc2, acc3);
}

// ---------------------------------------------------------------------------
extern "C" void kernel_launch(void* const* d_in, const int* in_sizes, int n_in,
                              void* d_out, int out_size, void* d_ws, size_t ws_size,
                              hipStream_t stream) {
    const float* hidden = (const float*)d_in[0];
    const float* ehs    = (const float*)d_in[1];
    const float* pos    = (const float*)d_in[2];
    const float* refp   = (const float*)d_in[3];
    const float* Wv   = (const float*)d_in[5];
    const float* bv   = (const float*)d_in[6];
    const float* Wo   = (const float*)d_in[7];
    const float* bo   = (const float*)d_in[8];
    const float* Wa   = (const float*)d_in[9];
    const float* ba   = (const float*)d_in[10];
    const float* Wout = (const float*)d_in[11];
    const float* bout = (const float*)d_in[12];

    float* ws = (float*)d_ws;
    unsigned short* WfragQK = (unsigned short*)ws;             // 98,304 bf16 (off + attn at +65536)
    unsigned short* WfragO  = (unsigned short*)(ws + 49152);   // 65,536 bf16
    float* off_raw = ws + 1843200;       // 1,843,200 f32
    float* logits  = ws + 3686400;       //   921,600 f32
    float* out_pre = ws + 4608000;       // 1,843,200 f32
    unsigned short* value = (unsigned short*)(ws + 6451200);  // 44,564,480 bf16
    // WfragV aliases out_pre's region: lifetime [wfrag_all, uber_gemm],
    // out_pre lifetime [sample_fused_k, gemm_out_mfma] — disjoint on the stream.
    unsigned short* WfragV = (unsigned short*)out_pre;         // 65,536 bf16

    float* outv = (float*)d_out;         // (B,Q,D) f32
    float* attw = outv + 1843200;        // (B,Q,NH,NL,NP) f32

    wfrag_all<<<112, 256, 0, stream>>>(Wv, Wout, Wo, Wa, WfragV, WfragO, WfragQK);
    uber_gemm<<<2833, 512, 0, stream>>>(ehs, WfragV, bv, value,
                                        hidden, pos, WfragQK, bo, ba,
                                        off_raw, logits, Bc * Qn);
    sample_fused_k<<<3600, 256, 0, stream>>>(value, off_raw, refp, logits, attw, out_pre);
    gemm_out_mfma<<<113, 512, 0, stream>>>(out_pre, WfragO, bout, outv, Bc * Qn);
}

// Round 19
// 144.647 us; speedup vs baseline: 1.1253x; 1.0942x over previous
//
#include <hip/hip_runtime.h>
#include <hip/hip_bf16.h>

// Problem constants (fixed by setup_inputs)
constexpr int Bc  = 8;
constexpr int Qn  = 900;
constexpr int Sn  = 21760;

__constant__ int LVL_START[4] = {0, 16384, 20480, 21504};

typedef __attribute__((ext_vector_type(8))) short short8;
typedef __attribute__((ext_vector_type(4))) float f32x4;

__device__ __forceinline__ unsigned short f2bf(float x) {
    union { float f; unsigned int u; } z; z.f = x;
    unsigned int r = (z.u + 0x7FFF + ((z.u >> 16) & 1)) >> 16;   // RTN-even
    return (unsigned short)r;
}
__device__ __forceinline__ float bf2f(unsigned short u) {
    union { unsigned int i; float f; } z;
    z.i = ((unsigned int)u) << 16;
    return z.f;
}

// Async global->LDS DMA, 16B per lane (wave-uniform LDS base + lane*16).
__device__ __forceinline__ void gload_lds16(const float* gsrc, float* ldst) {
    __builtin_amdgcn_global_load_lds(
        (const __attribute__((address_space(1))) void*)gsrc,
        (__attribute__((address_space(3))) void*)ldst,
        16, 0, 0);
}

// ---------------------------------------------------------------------------
// Single pre-pass packing all four weights into bf16 MFMA fragment order.
// Block roles: 0-31 Wv(256) | 32-63 Wout(256) | 64-95 Wo(256) | 96-111 Wa(128).
__global__ __launch_bounds__(256) void wfrag_all(const float* __restrict__ Wv,
                                                 const float* __restrict__ Wout,
                                                 const float* __restrict__ Wo,
                                                 const float* __restrict__ Wa,
                                                 unsigned short* __restrict__ fV,
                                                 unsigned short* __restrict__ fO,
                                                 unsigned short* __restrict__ fQK) {
    int blk = blockIdx.x;
    const float* W; unsigned short* out; int N, base;
    if      (blk < 32) { W = Wv;   out = fV;           N = 256; base = 0;  }
    else if (blk < 64) { W = Wout; out = fO;           N = 256; base = 32; }
    else if (blk < 96) { W = Wo;   out = fQK;          N = 256; base = 64; }
    else               { W = Wa;   out = fQK + 65536;  N = 128; base = 96; }
    int gid = (blk - base) * 256 + threadIdx.x;
    int frag = gid >> 6, lane = gid & 63;
    int ntile = frag >> 3, s = frag & 7;
    int n = ntile * 16 + (lane & 15);
    int kb = s * 32 + (lane >> 4) * 8;
    unsigned short* o = out + (size_t)gid * 8;
#pragma unroll
    for (int j = 0; j < 8; ++j)
        o[j] = f2bf(W[(size_t)(kb + j) * N + n]);
}

// ---------------------------------------------------------------------------
// UBER GEMM: one dispatch, two block roles.
//   blocks 0..2719   : value = ehs @ W_value + b (bf16 out)
//     A staged via ASYNC global_load_lds (f32, 64 KB LDS; the one untried
//     lever after r6-r13's reg-staged variants all pinned at 104-117us).
//     Both-sides swizzle (rule #21): linear LDS dest, global src chunk
//     lane^j, read chunk c^(row&7) — involution; ~2-way bank conflict.
//     f32->bf16 cvt at consume time (v_cvt_pk RNE, ~64 ops/wave).
//   blocks 2720..2832: {off_raw, logits} = (hidden+pos) @ {W_off, W_attn}
__global__ __launch_bounds__(512) void uber_gemm(
        const float* __restrict__ Aehs, const unsigned short* __restrict__ WfragV,
        const float* __restrict__ bv, unsigned short* __restrict__ Cval,
        const float* __restrict__ A1, const float* __restrict__ A2,
        const unsigned short* __restrict__ WfragQK,
        const float* __restrict__ bo, const float* __restrict__ ba,
        float* __restrict__ off_raw, float* __restrict__ logits, int Mqk) {
    __shared__ float smem[64 * 256];          // 64 KB (value: f32; qk: bf16 in low 32 KB)

    const int t    = threadIdx.x;
    const int lane = t & 63;
    const int w    = t >> 6;                  // 0..7
    const int wr   = w >> 2, wc = w & 3;      // wave grid 2x4
    const int lq   = lane >> 4, lr = lane & 15;

    if (blockIdx.x < 2720) {
        // ================= VALUE role =================
        const int bm = blockIdx.x;
        const float* Ab = Aehs + (size_t)bm * 64 * 256;

        // Stage: wave w stages rows w*8..w*8+7, one async 1KB DMA per row.
        // LDS position (row, chunk ci) holds global chunk ci^(row&7)
        // (row&7 == j since row = w*8+j).
#pragma unroll
        for (int j = 0; j < 8; ++j) {
            int row = w * 8 + j;
            gload_lds16(Ab + row * 256 + ((lane ^ j) << 2), &smem[row * 256]);
        }

        f32x4 acc[2][4];
#pragma unroll
        for (int mt = 0; mt < 2; ++mt)
#pragma unroll
            for (int nt = 0; nt < 4; ++nt) acc[mt][nt] = (f32x4){0.f, 0.f, 0.f, 0.f};

        __syncthreads();   // drains the DMA (vmcnt) + joins waves

#pragma unroll 2
        for (int s = 0; s < 8; ++s) {
            short8 bfr[4];
#pragma unroll
            for (int nt = 0; nt < 4; ++nt) {
                int ntile = wc * 4 + nt;
                size_t off = ((size_t)((ntile * 8 + s) * 64 + lane)) * 8;
                bfr[nt] = *reinterpret_cast<const short8*>(WfragV + off);
            }
#pragma unroll
            for (int mt = 0; mt < 2; ++mt) {
                const int r  = wr * 32 + mt * 16 + lr;
                const int r7 = r & 7;
                const int c  = s * 8 + lq * 2;            // 16B-chunk index in row
                f32x4 lo = *reinterpret_cast<const f32x4*>(&smem[r * 256 + ((c ^ r7) << 2)]);
                f32x4 hi = *reinterpret_cast<const f32x4*>(&smem[r * 256 + (((c + 1) ^ r7) << 2)]);
                union { short8 v; __hip_bfloat162 h[4]; } af;
                af.h[0] = __float22bfloat162_rn(make_float2(lo.x, lo.y));
                af.h[1] = __float22bfloat162_rn(make_float2(lo.z, lo.w));
                af.h[2] = __float22bfloat162_rn(make_float2(hi.x, hi.y));
                af.h[3] = __float22bfloat162_rn(make_float2(hi.z, hi.w));
#pragma unroll
                for (int nt = 0; nt < 4; ++nt)
                    acc[mt][nt] = __builtin_amdgcn_mfma_f32_16x16x32_bf16(bfr[nt], af.v, acc[mt][nt], 0, 0, 0);
            }
        }

#pragma unroll
        for (int nt = 0; nt < 4; ++nt) {
            int n0 = wc * 64 + nt * 16 + lq * 4;
            float4 bb = *reinterpret_cast<const float4*>(&bv[n0]);
#pragma unroll
            for (int mt = 0; mt < 2; ++mt) {
                int row = bm * 64 + wr * 32 + mt * 16 + lr;
                ushort4 o;
                o.x = f2bf(acc[mt][nt][0] + bb.x);
                o.y = f2bf(acc[mt][nt][1] + bb.y);
                o.z = f2bf(acc[mt][nt][2] + bb.z);
                o.w = f2bf(acc[mt][nt][3] + bb.w);
                *reinterpret_cast<ushort4*>(&Cval[(size_t)row * 256 + n0]) = o;
            }
        }
    } else {
        // ================= QK role =================
        unsigned short* As = reinterpret_cast<unsigned short*>(smem);
        const int bm = blockIdx.x - 2720;
        const int maxr = Mqk - bm * 64;

        const float4* A14 = reinterpret_cast<const float4*>(A1 + (size_t)bm * 64 * 256);
        const float4* A24 = reinterpret_cast<const float4*>(A2 + (size_t)bm * 64 * 256);
#pragma unroll
        for (int i = 0; i < 4; ++i) {
            int c = i * 512 + t;
            int row = c >> 5;
            int kus = (c & 31) * 8;
            float4 v0 = make_float4(0.f,0.f,0.f,0.f), v1 = v0;
            if (row < maxr) {
                float4 x0 = A14[c * 2], y0 = A24[c * 2];
                float4 x1 = A14[c * 2 + 1], y1 = A24[c * 2 + 1];
                v0 = make_float4(x0.x + y0.x, x0.y + y0.y, x0.z + y0.z, x0.w + y0.w);
                v1 = make_float4(x1.x + y1.x, x1.y + y1.y, x1.z + y1.z, x1.w + y1.w);
            }
            union { short8 v; unsigned short u[8]; } pk;
            pk.u[0] = f2bf(v0.x); pk.u[1] = f2bf(v0.y); pk.u[2] = f2bf(v0.z); pk.u[3] = f2bf(v0.w);
            pk.u[4] = f2bf(v1.x); pk.u[5] = f2bf(v1.y); pk.u[6] = f2bf(v1.z); pk.u[7] = f2bf(v1.w);
            int idx = row * 256 + (kus ^ ((row & 7) << 3));
            *reinterpret_cast<short8*>(&As[idx]) = pk.v;
        }

        f32x4 acc[2][6];
#pragma unroll
        for (int mt = 0; mt < 2; ++mt)
#pragma unroll
            for (int nt = 0; nt < 6; ++nt) acc[mt][nt] = (f32x4){0.f, 0.f, 0.f, 0.f};

        __syncthreads();

#pragma unroll 2
        for (int s = 0; s < 8; ++s) {
            short8 bfr[6];
#pragma unroll
            for (int nt = 0; nt < 6; ++nt) {
                int ntc = wc * 6 + nt;                // 0..23
                const unsigned short* p = (ntc < 16)
                    ? WfragQK + ((size_t)(ntc * 8 + s)) * 512
                    : WfragQK + 65536 + ((size_t)((ntc - 16) * 8 + s)) * 512;
                bfr[nt] = *reinterpret_cast<const short8*>(p + lane * 8);
            }
            const int kus = s * 32 + lq * 8;
#pragma unroll
            for (int mt = 0; mt < 2; ++mt) {
                int r   = wr * 32 + mt * 16 + lr;
                int idx = r * 256 + (kus ^ ((r & 7) << 3));
                short8 a = *reinterpret_cast<const short8*>(&As[idx]);
#pragma unroll
                for (int nt = 0; nt < 6; ++nt)
                    acc[mt][nt] = __builtin_amdgcn_mfma_f32_16x16x32_bf16(bfr[nt], a, acc[mt][nt], 0, 0, 0);
            }
        }

#pragma unroll
        for (int nt = 0; nt < 6; ++nt) {
            int ntc = wc * 6 + nt;
            float* base; int stride, n0;
            float4 bb;
            if (ntc < 16) { n0 = ntc * 16 + lq * 4;        base = off_raw; stride = 256;
                            bb = *reinterpret_cast<const float4*>(&bo[n0]); }
            else          { n0 = (ntc - 16) * 16 + lq * 4; base = logits;  stride = 128;
                            bb = *reinterpret_cast<const float4*>(&ba[n0]); }
#pragma unroll
            for (int mt = 0; mt < 2; ++mt) {
                int r = wr * 32 + mt * 16 + lr;
                if (r < maxr) {
                    int row = bm * 64 + r;
                    float4 o = make_float4(acc[mt][nt][0] + bb.x, acc[mt][nt][1] + bb.y,
                                           acc[mt][nt][2] + bb.z, acc[mt][nt][3] + bb.w);
                    *reinterpret_cast<float4*>(&base[(size_t)row * stride + n0]) = o;
                }
            }
        }
    }
}

// ---------------------------------------------------------------------------
// out = out_pre @ W_out + b via bf16 MFMA, f32 output. M=7200, row-guarded.
__global__ __launch_bounds__(512) void gemm_out_mfma(const float* __restrict__ A,
                                                     const unsigned short* __restrict__ Wfrag,
                                                     const float* __restrict__ bias,
                                                     float* __restrict__ C, int M) {
    __shared__ unsigned short As[64 * 256];

    const int t  = threadIdx.x;
    const int bm = blockIdx.x;
    const int maxr = M - bm * 64;

    const float4* A4 = reinterpret_cast<const float4*>(A + (size_t)bm * 64 * 256);
#pragma unroll
    for (int i = 0; i < 4; ++i) {
        int c = i * 512 + t;
        int row = c >> 5;
        int kus = (c & 31) * 8;
        float4 v0 = make_float4(0.f,0.f,0.f,0.f), v1 = v0;
        if (row < maxr) { v0 = A4[c * 2]; v1 = A4[c * 2 + 1]; }
        union { short8 v; unsigned short u[8]; } pk;
        pk.u[0] = f2bf(v0.x); pk.u[1] = f2bf(v0.y); pk.u[2] = f2bf(v0.z); pk.u[3] = f2bf(v0.w);
        pk.u[4] = f2bf(v1.x); pk.u[5] = f2bf(v1.y); pk.u[6] = f2bf(v1.z); pk.u[7] = f2bf(v1.w);
        int idx = row * 256 + (kus ^ ((row & 7) << 3));
        *reinterpret_cast<short8*>(&As[idx]) = pk.v;
    }

    const int lane = t & 63;
    const int w    = t >> 6;
    const int wr   = w >> 2, wc = w & 3;
    const int lq   = lane >> 4, lr = lane & 15;

    f32x4 acc[2][4];
#pragma unroll
    for (int mt = 0; mt < 2; ++mt)
#pragma unroll
        for (int nt = 0; nt < 4; ++nt) acc[mt][nt] = (f32x4){0.f, 0.f, 0.f, 0.f};

    __syncthreads();

#pragma unroll 2
    for (int s = 0; s < 8; ++s) {
        short8 bfr[4];
#pragma unroll
        for (int nt = 0; nt < 4; ++nt) {
            int ntile = wc * 4 + nt;
            size_t off = ((size_t)((ntile * 8 + s) * 64 + lane)) * 8;
            bfr[nt] = *reinterpret_cast<const short8*>(Wfrag + off);
        }
        const int kus = s * 32 + lq * 8;
#pragma unroll
        for (int mt = 0; mt < 2; ++mt) {
            int r   = wr * 32 + mt * 16 + lr;
            int idx = r * 256 + (kus ^ ((r & 7) << 3));
            short8 a = *reinterpret_cast<const short8*>(&As[idx]);
#pragma unroll
            for (int nt = 0; nt < 4; ++nt)
                acc[mt][nt] = __builtin_amdgcn_mfma_f32_16x16x32_bf16(bfr[nt], a, acc[mt][nt], 0, 0, 0);
        }
    }

#pragma unroll
    for (int nt = 0; nt < 4; ++nt) {
        int n0 = wc * 64 + nt * 16 + lq * 4;
        float4 bb = *reinterpret_cast<const float4*>(&bias[n0]);
#pragma unroll
        for (int mt = 0; mt < 2; ++mt) {
            int r = wr * 32 + mt * 16 + lr;
            if (r < maxr) {
                int row = bm * 64 + r;
                float4 o = make_float4(acc[mt][nt][0] + bb.x, acc[mt][nt][1] + bb.y,
                                       acc[mt][nt][2] + bb.z, acc[mt][nt][3] + bb.w);
                *reinterpret_cast<float4*>(&C[(size_t)row * 256 + n0]) = o;
            }
        }
    }
}

// ---------------------------------------------------------------------------
// Fused softmax + bilinear sampling. 16 lanes per (b,q,h) group:
//   ch = L&7 -> 4-channel group; pq = L>>3 -> level-pair half.
__global__ __launch_bounds__(256) void sample_fused_k(const unsigned short* __restrict__ value,
                                                      const float* __restrict__ off_raw,
                                                      const float* __restrict__ refp,
                                                      const float* __restrict__ logits,
                                                      float* __restrict__ attw,
                                                      float* __restrict__ out_pre) {
    const int L    = threadIdx.x & 15;
    const int g    = threadIdx.x >> 4;         // 0..15
    const int idx  = blockIdx.x * 16 + g;      // (b*Q+q)*8 + h, < 57600
    const int h    = idx & 7;
    const int bq   = idx >> 3;
    const int b    = bq / Qn;
    const int ch   = L & 7;
    const int pq   = L >> 3;

    // ---- inline softmax over this group's 16 logits ----
    const float4* lg = reinterpret_cast<const float4*>(logits + (size_t)idx * 16);
    float v[16];
    float4 a0 = lg[0], a1 = lg[1], a2 = lg[2], a3 = lg[3];
    v[0]=a0.x; v[1]=a0.y; v[2]=a0.z; v[3]=a0.w;
    v[4]=a1.x; v[5]=a1.y; v[6]=a1.z; v[7]=a1.w;
    v[8]=a2.x; v[9]=a2.y; v[10]=a2.z; v[11]=a2.w;
    v[12]=a3.x; v[13]=a3.y; v[14]=a3.z; v[15]=a3.w;
    float m = v[0];
#pragma unroll
    for (int i = 1; i < 16; ++i) m = fmaxf(m, v[i]);
    float s = 0.f;
#pragma unroll
    for (int i = 0; i < 16; ++i) { v[i] = __expf(v[i] - m); s += v[i]; }
    float inv = 1.f / s;
#pragma unroll
    for (int i = 0; i < 16; ++i) v[i] *= inv;

    // attw output (B,Q,NH,16): lanes pq==0, ch<4 each write one float4
    if (pq == 0 && ch < 4) {
        float4 o;
        if      (ch == 0) o = make_float4(v[0],  v[1],  v[2],  v[3]);
        else if (ch == 1) o = make_float4(v[4],  v[5],  v[6],  v[7]);
        else if (ch == 2) o = make_float4(v[8],  v[9],  v[10], v[11]);
        else              o = make_float4(v[12], v[13], v[14], v[15]);
        reinterpret_cast<float4*>(attw + (size_t)idx * 16)[ch] = o;
    }

    // this half's 8 weights, statically selected
    float w8[8];
#pragma unroll
    for (int i = 0; i < 8; ++i) w8[i] = (pq == 0) ? v[i] : v[i + 8];

    const ushort4* v4 = reinterpret_cast<const ushort4*>(value);
    const size_t vbase4 = (size_t)b * (Sn * 64) + h * 8 + ch;
    const float* offs = off_raw + (size_t)bq * 256 + h * 32;
    const float* rp   = refp    + (size_t)bq * 8;

    float acc0 = 0.f, acc1 = 0.f, acc2 = 0.f, acc3 = 0.f;

#pragma unroll
    for (int li = 0; li < 2; ++li) {
        const int lvl = pq * 2 + li;
        const int Wl = 128 >> lvl, Hl = 128 >> lvl;
        const float fW = (float)Wl, fH = (float)Hl;
        const float rx = rp[lvl * 2 + 0], ry = rp[lvl * 2 + 1];
        const size_t lb4 = vbase4 + (size_t)LVL_START[lvl] * 64;
#pragma unroll
        for (int p = 0; p < 4; ++p) {
            const float w  = w8[li * 4 + p];
            const float locx = rx + offs[lvl * 8 + p * 2 + 0] / fW;
            const float locy = ry + offs[lvl * 8 + p * 2 + 1] / fH;
            const float x = locx * fW - 0.5f;
            const float y = locy * fH - 0.5f;
            const float x0f = floorf(x), y0f = floorf(y);
            const int x0 = (int)x0f, y0 = (int)y0f;
            const int x1 = x0 + 1, y1 = y0 + 1;
            const float fx = x - x0f, fy = y - y0f;
            const float vx0 = (x0 >= 0 && x0 < Wl) ? 1.f : 0.f;
            const float vx1 = (x1 >= 0 && x1 < Wl) ? 1.f : 0.f;
            const float vy0 = (y0 >= 0 && y0 < Hl) ? 1.f : 0.f;
            const float vy1 = (y1 >= 0 && y1 < Hl) ? 1.f : 0.f;
            const int xc0 = min(max(x0, 0), Wl - 1);
            const int xc1 = min(max(x1, 0), Wl - 1);
            const int yc0 = min(max(y0, 0), Hl - 1);
            const int yc1 = min(max(y1, 0), Hl - 1);
            const float w00 = w * (1.f - fx) * (1.f - fy) * vx0 * vy0;
            const float w01 = w * fx         * (1.f - fy) * vx1 * vy0;
            const float w10 = w * (1.f - fx) * fy         * vx0 * vy1;
            const float w11 = w * fx         * fy         * vx1 * vy1;

            const ushort4 t00 = v4[lb4 + (size_t)(yc0 * Wl + xc0) * 64];
            const ushort4 t01 = v4[lb4 + (size_t)(yc0 * Wl + xc1) * 64];
            const ushort4 t10 = v4[lb4 + (size_t)(yc1 * Wl + xc0) * 64];
            const ushort4 t11 = v4[lb4 + (size_t)(yc1 * Wl + xc1) * 64];

            acc0 += w00 * bf2f(t00.x) + w01 * bf2f(t01.x) + w10 * bf2f(t10.x) + w11 * bf2f(t11.x);
            acc1 += w00 * bf2f(t00.y) + w01 * bf2f(t01.y) + w10 * bf2f(t10.y) + w11 * bf2f(t11.y);
            acc2 += w00 * bf2f(t00.z) + w01 * bf2f(t01.z) + w10 * bf2f(t10.z) + w11 * bf2f(t11.z);
            acc3 += w00 * bf2f(t00.w) + w01 * bf2f(t01.w) + w10 * bf2f(t10.w) + w11 * bf2f(t11.w);
        }
    }

    // reduce the two point-halves (partner = lane^8, within the 16-lane group)
    acc0 += __shfl_xor(acc0, 8);
    acc1 += __shfl_xor(acc1, 8);
    acc2 += __shfl_xor(acc2, 8);
    acc3 += __shfl_xor(acc3, 8);

    if (pq == 0)
        reinterpret_cast<float4*>(out_pre)[(size_t)bq * 64 + h * 8 + ch] =
            make_float4(acc0, acc1, acc2, acc3);
}

// ---------------------------------------------------------------------------
extern "C" void kernel_launch(void* const* d_in, const int* in_sizes, int n_in,
                              void* d_out, int out_size, void* d_ws, size_t ws_size,
                              hipStream_t stream) {
    const float* hidden = (const float*)d_in[0];
    const float* ehs    = (const float*)d_in[1];
    const float* pos    = (const float*)d_in[2];
    const float* refp   = (const float*)d_in[3];
    const float* Wv   = (const float*)d_in[5];
    const float* bv   = (const float*)d_in[6];
    const float* Wo   = (const float*)d_in[7];
    const float* bo   = (const float*)d_in[8];
    const float* Wa   = (const float*)d_in[9];
    const float* ba   = (const float*)d_in[10];
    const float* Wout = (const float*)d_in[11];
    const float* bout = (const float*)d_in[12];

    float* ws = (float*)d_ws;
    unsigned short* WfragQK = (unsigned short*)ws;             // 98,304 bf16 (off + attn at +65536)
    unsigned short* WfragO  = (unsigned short*)(ws + 49152);   // 65,536 bf16
    float* off_raw = ws + 1843200;       // 1,843,200 f32
    float* logits  = ws + 3686400;       //   921,600 f32
    float* out_pre = ws + 4608000;       // 1,843,200 f32
    unsigned short* value = (unsigned short*)(ws + 6451200);  // 44,564,480 bf16
    // WfragV aliases out_pre's region: lifetime [wfrag_all, uber_gemm],
    // out_pre lifetime [sample_fused_k, gemm_out_mfma] — disjoint on the stream.
    unsigned short* WfragV = (unsigned short*)out_pre;         // 65,536 bf16

    float* outv = (float*)d_out;         // (B,Q,D) f32
    float* attw = outv + 1843200;        // (B,Q,NH,NL,NP) f32

    wfrag_all<<<112, 256, 0, stream>>>(Wv, Wout, Wo, Wa, WfragV, WfragO, WfragQK);
    uber_gemm<<<2833, 512, 0, stream>>>(ehs, WfragV, bv, value,
                                        hidden, pos, WfragQK, bo, ba,
                                        off_raw, logits, Bc * Qn);
    sample_fused_k<<<3600, 256, 0, stream>>>(value, off_raw, refp, logits, attw, out_pre);
    gemm_out_mfma<<<113, 512, 0, stream>>>(out_pre, WfragO, bout, outv, Bc * Qn);
}